// Round 5
// baseline (292.991 us; speedup 1.0000x reference)
//
#include <hip/hip_runtime.h>
#include <hip/hip_fp16.h>
#include <cstdint>

typedef unsigned short ushort_t;
typedef _Float16 f16x8 __attribute__((ext_vector_type(8)));  // 8 f16 (4 VGPRs) for MFMA
typedef float f32x4 __attribute__((ext_vector_type(4)));
typedef unsigned int u32x4 __attribute__((ext_vector_type(4)));

#define M_TOT  32768
#define K_EMB  256
#define K_CORE 512
#define ACT    12

__device__ __forceinline__ unsigned int pack2h(float a, float b) {
    __half2 h = __floats2half2_rn(a, b);
    union { __half2 h2; unsigned int u; } v; v.h2 = h; return v.u;
}

union h8cvt { u32x4 u; f16x8 h; };

// ---------- kernel 1 (merged prep) ----------
// blocks 0..63: transpose W1[0:256,:] into the LANE-PERMUTED slab layout:
//   element (n, k) -> slab it = (n>>7)*8 + (k>>5)          (64 slabs of 8 KB)
//                     chunk  rgrp = (n>>4)&7               (8 chunks of 1 KB)
//                     within-chunk lane ℓ = ((k>>3)&3)*16 + (n&15), elem e = k&7
//   addr (ushorts) = it*4096 + rgrp*512 + ℓ*8 + e
// A wave reading chunk base + ℓ*16B gets a fully-contiguous 1 KB AND each lane
// (lane16=n&15, qd=(k>>3)&3) receives exactly its MFMA A-position fragment.
// blocks 64..319: cp[b][n] = b1[n] + sum_k core[b][k]*W1[256+k][n], K-split x4.
__global__ __launch_bounds__(1024) void prep_k(const float* __restrict__ W1,
                                               ushort_t* __restrict__ W1T,
                                               const float* __restrict__ core,
                                               const float* __restrict__ b1,
                                               float* __restrict__ cp) {
    __shared__ float tile[64][65];
    __shared__ float part[3][256];
    const int id = blockIdx.x;
    const int t = threadIdx.x;
    if (id < 64) {
        // ---- transpose+convert one 64x64 tile (1024 threads: 1 float4 load, 1 uint2 store) ----
        const int k0 = (id & 3) * 64, n0 = (id >> 2) * 64;
        const int r = t >> 4, c4 = (t & 15) * 4;
        const float4 v = *(const float4*)(W1 + (size_t)(k0 + r) * 1024 + n0 + c4);
        tile[r][c4 + 0] = v.x; tile[r][c4 + 1] = v.y;
        tile[r][c4 + 2] = v.z; tile[r][c4 + 3] = v.w;
        __syncthreads();
        uint2 o;
        o.x = pack2h(tile[c4 + 0][r], tile[c4 + 1][r]);
        o.y = pack2h(tile[c4 + 2][r], tile[c4 + 3][r]);
        const int n  = n0 + r;          // 0..1023
        const int kk = k0 + c4;         // 0..255, multiple of 4
        const int it   = ((n >> 7) << 3) + (kk >> 5);
        const int rgrp = (n >> 4) & 7;
        const int lane = (((kk >> 3) & 3) << 4) + (n & 15);
        const size_t addr = (size_t)it * 4096 + rgrp * 512 + lane * 8 + (kk & 7);
        *(uint2*)(W1T + addr) = o;
    } else {
        // ---- corepart: 4-way K-split, 16 waves/block for latency hiding ----
        const int xb = id - 64;
        const int b = xb >> 2;                 // 0..63
        const int nl = t & 255;
        const int n = (xb & 3) * 256 + nl;     // 0..1023
        const int kq = t >> 8;                 // 0..3, each owns 128 k
        const float* cr = core + (size_t)b * K_CORE + kq * 128;
        const float* wp = W1 + (size_t)(K_EMB + kq * 128) * 1024 + n;
        float s0 = 0.f, s1 = 0.f, s2 = 0.f, s3 = 0.f;
#pragma unroll 8
        for (int k = 0; k < 128; k += 4) {
            s0 += cr[k + 0] * wp[(size_t)(k + 0) * 1024];
            s1 += cr[k + 1] * wp[(size_t)(k + 1) * 1024];
            s2 += cr[k + 2] * wp[(size_t)(k + 2) * 1024];
            s3 += cr[k + 3] * wp[(size_t)(k + 3) * 1024];
        }
        const float s = (s0 + s1) + (s2 + s3);
        if (kq) part[kq - 1][nl] = s;
        __syncthreads();
        if (kq == 0)
            cp[b * 1024 + n] = b1[n] + s + part[0][nl] + part[1][nl] + part[2][nl];
    }
}

// ---------- kernel 2 (fused): NO LDS in the hot path, ONE barrier total.
// 1024 blocks x 256 threads; block owns 32 m-rows; wave w owns n-quarter
// [w*256, w*256+256). 4096 waves -> 12 waves/CU at 3 blocks/CU (VGPR-capped only).
// A (32 rows x 256 k) lives in 64 VGPRs per wave, loaded once from emb.
// B fragments stream global->VGPR from the lane-permuted slab w1t: one fully
// contiguous 1 KB load per instruction (keeps w1t L2-resident, round-4 property).
// Inner loop = {2 loads + 4 MFMA}, fully unrolled, compiler-scheduled.
__global__ __launch_bounds__(256, 3) void fused_k(const float* __restrict__ emb,
                                                  const ushort_t* __restrict__ w1t,
                                                  const float* __restrict__ cp,
                                                  const float* __restrict__ W2,
                                                  const float* __restrict__ b2,
                                                  const int* __restrict__ nr_units,
                                                  const int* __restrict__ nr_flags,
                                                  float* __restrict__ out0,
                                                  float* __restrict__ out1) {
    __shared__ __align__(16) float logitP[4][32][ACT];   // 6 KB, per-wave slots

    const int t = threadIdx.x;
    const int w = t >> 6, L = t & 63;
    const int lane16 = L & 15, qd = L >> 4;
    const int m0 = blockIdx.x * 32;
    const int bb = blockIdx.x >> 4;

    // ---- A into registers: 2 mi x 8 ks fragments (64 VGPRs) ----
    f16x8 af[2][8];
#pragma unroll
    for (int mi = 0; mi < 2; ++mi) {
        const float* ar = emb + (size_t)(m0 + mi * 16 + lane16) * K_EMB + qd * 8;
#pragma unroll
        for (int ks = 0; ks < 8; ++ks) {
            const f32x4 lo = __builtin_nontemporal_load((const f32x4*)(ar + ks * 32));
            const f32x4 hi = __builtin_nontemporal_load((const f32x4*)(ar + ks * 32) + 1);
            h8cvt pk;
            pk.u[0] = pack2h(lo[0], lo[1]); pk.u[1] = pack2h(lo[2], lo[3]);
            pk.u[2] = pack2h(hi[0], hi[1]); pk.u[3] = pack2h(hi[2], hi[3]);
            af[mi][ks] = pk.h;
        }
    }

    // ---- logit partials ----
    f32x4 la[2][3];
#pragma unroll
    for (int mi = 0; mi < 2; ++mi)
#pragma unroll
        for (int c = 0; c < 3; ++c) la[mi][c] = (f32x4){0.f, 0.f, 0.f, 0.f};

    // ---- main loop: 8 n-chunks of 32 within this wave's quarter ----
#pragma unroll
    for (int nc = 0; nc < 8; ++nc) {
        f32x4 acc[2][2];                 // [ni][mi]: D row=n(qd*4+r), col=m(lane16)
#pragma unroll
        for (int ni = 0; ni < 2; ++ni)
#pragma unroll
            for (int mi = 0; mi < 2; ++mi) acc[ni][mi] = (f32x4){0.f, 0.f, 0.f, 0.f};

        // slab pointer: it = (w*2 + nc/4)*8 + ks; chunk rgrp = (nc&3)*2 + ni
        const ushort_t* sb = w1t + (size_t)(w * 2 + (nc >> 2)) * 8 * 4096
                                 + ((nc & 3) * 2) * 512 + L * 8;
#pragma unroll
        for (int ks = 0; ks < 8; ++ks) {
            const f16x8 bf0 = *(const f16x8*)(sb + ks * 4096);
            const f16x8 bf1 = *(const f16x8*)(sb + ks * 4096 + 512);
            acc[0][0] = __builtin_amdgcn_mfma_f32_16x16x32_f16(bf0, af[0][ks], acc[0][0], 0, 0, 0);
            acc[0][1] = __builtin_amdgcn_mfma_f32_16x16x32_f16(bf0, af[1][ks], acc[0][1], 0, 0, 0);
            acc[1][0] = __builtin_amdgcn_mfma_f32_16x16x32_f16(bf1, af[0][ks], acc[1][0], 0, 0, 0);
            acc[1][1] = __builtin_amdgcn_mfma_f32_16x16x32_f16(bf1, af[1][ks], acc[1][1], 0, 0, 0);
        }

        // ---- epilogue: +cp, relu, float4 out1 stores, logit partials ----
#pragma unroll
        for (int ni = 0; ni < 2; ++ni) {
            const int nbase = w * 256 + nc * 32 + ni * 16 + qd * 4;
            const f32x4 cpv = *(const f32x4*)(cp + bb * 1024 + nbase);
#pragma unroll
            for (int mi = 0; mi < 2; ++mi) {
                f32x4 v = acc[ni][mi] + cpv;
#pragma unroll
                for (int j = 0; j < 4; ++j) v[j] = v[j] > 0.f ? v[j] : 0.f;
                acc[ni][mi] = v;
                const size_t m = (size_t)(m0 + mi * 16 + lane16);
                __builtin_nontemporal_store(v, (f32x4*)(out1 + m * 1024 + nbase));
            }
#pragma unroll
            for (int r = 0; r < 4; ++r) {
                const f32x4* wp = (const f32x4*)(W2 + (size_t)(nbase + r) * ACT);
                const f32x4 w2a = wp[0], w2b = wp[1], w2c = wp[2];
#pragma unroll
                for (int mi = 0; mi < 2; ++mi) {
                    const float vv = acc[ni][mi][r];
                    la[mi][0] += w2a * vv;
                    la[mi][1] += w2b * vv;
                    la[mi][2] += w2c * vv;
                }
            }
        }
    }

    // ---- reduce logit partials across qd (lanes sharing lane16) ----
#pragma unroll
    for (int mi = 0; mi < 2; ++mi)
#pragma unroll
        for (int c = 0; c < 3; ++c)
#pragma unroll
            for (int j = 0; j < 4; ++j) {
                la[mi][c][j] += __shfl_xor(la[mi][c][j], 16, 64);
                la[mi][c][j] += __shfl_xor(la[mi][c][j], 32, 64);
            }
    if (qd == 0) {
#pragma unroll
        for (int mi = 0; mi < 2; ++mi) {
            f32x4* p = (f32x4*)&logitP[w][mi * 16 + lane16][0];
            p[0] = la[mi][0]; p[1] = la[mi][1]; p[2] = la[mi][2];
        }
    }
    __syncthreads();   // the ONLY barrier

    // ---- softmax + range mask, one thread per row ----
    if (t < 32) {
        float lg[ACT];
#pragma unroll
        for (int a = 0; a < ACT; ++a)
            lg[a] = logitP[0][t][a] + logitP[1][t][a]
                  + logitP[2][t][a] + logitP[3][t][a] + b2[a];
        float mx = lg[0];
#pragma unroll
        for (int a = 1; a < ACT; ++a) mx = fmaxf(mx, lg[a]);
        float s = 0.f;
#pragma unroll
        for (int a = 0; a < ACT; ++a) { lg[a] = __expf(lg[a] - mx); s += lg[a]; }
        const float inv = 1.f / s;
        const int m = m0 + t;
        const int u = m & 511;
        const float msk = (u >= nr_flags[bb] && u < nr_units[bb]) ? 1.0f : 1e-9f;
        f32x4 o0, o1, o2;
#pragma unroll
        for (int j = 0; j < 4; ++j) {
            o0[j] = lg[j] * inv * msk;
            o1[j] = lg[j + 4] * inv * msk;
            o2[j] = lg[j + 8] * inv * msk;
        }
        f32x4* op = (f32x4*)(out0 + (size_t)m * ACT);
        __builtin_nontemporal_store(o0, op + 0);
        __builtin_nontemporal_store(o1, op + 1);
        __builtin_nontemporal_store(o2, op + 2);
    }
}

extern "C" void kernel_launch(void* const* d_in, const int* in_sizes, int n_in,
                              void* d_out, int out_size, void* d_ws, size_t ws_size,
                              hipStream_t stream) {
    const float* core   = (const float*)d_in[0];
    const float* emb    = (const float*)d_in[1];
    const int* nr_units = (const int*)d_in[2];
    const int* nr_flags = (const int*)d_in[3];
    const float* W1     = (const float*)d_in[4];
    const float* b1     = (const float*)d_in[5];
    const float* W2     = (const float*)d_in[6];
    const float* b2     = (const float*)d_in[7];

    float* out0 = (float*)d_out;                       // probs [32768*12] f32
    float* out1 = out0 + (size_t)M_TOT * ACT;          // embedding [32768*1024] f32

    ushort_t* w1t = (ushort_t*)d_ws;                   // f16, lane-permuted slabs, 512 KB
    float* cp = (float*)((char*)d_ws + (size_t)1024 * 256 * 2); // [64][1024] f32

    prep_k<<<dim3(320), 1024, 0, stream>>>(W1, w1t, core, b1, cp);
    fused_k<<<dim3(1024), 256, 0, stream>>>(emb, w1t, cp, W2, b2, nr_units, nr_flags, out0, out1);
}

// Round 6
// 245.553 us; speedup vs baseline: 1.1932x; 1.1932x over previous
//
#include <hip/hip_runtime.h>
#include <hip/hip_fp16.h>
#include <cstdint>

typedef unsigned short ushort_t;
typedef _Float16 f16x8 __attribute__((ext_vector_type(8)));  // 8 f16 (4 VGPRs) for MFMA
typedef float f32x4 __attribute__((ext_vector_type(4)));
typedef unsigned int u32x4 __attribute__((ext_vector_type(4)));

#define M_TOT  32768
#define K_EMB  256
#define K_CORE 512
#define ACT    12

__device__ __forceinline__ unsigned int pack2h(float a, float b) {
    __half2 h = __floats2half2_rn(a, b);
    union { __half2 h2; unsigned int u; } v; v.h2 = h; return v.u;
}

// ---------- kernel 1 (merged prep) ----------
// blocks 0..63: transpose W1[0:256,:] into the LANE-PERMUTED slab layout:
//   element (n, k) -> slab it = (n>>7)*8 + (k>>5)          (64 slabs of 8 KB)
//                     chunk  rgrp = (n>>4)&7               (8 chunks of 1 KB)
//                     within-chunk lane l = ((k>>3)&3)*16 + (n&15), elem e = k&7
//   addr (ushorts) = it*4096 + rgrp*512 + l*8 + e
// A wave reading chunk base + l*16B gets a fully-contiguous 1 KB AND each lane
// (lane16=n&15, qd=(k>>3)&3) receives exactly its MFMA B-position fragment.
// blocks 64..319: cp[b][n] = b1[n] + sum_k core[b][k]*W1[256+k][n], K-split x4.
__global__ __launch_bounds__(1024) void prep_k(const float* __restrict__ W1,
                                               ushort_t* __restrict__ W1T,
                                               const float* __restrict__ core,
                                               const float* __restrict__ b1,
                                               float* __restrict__ cp) {
    __shared__ float tile[64][65];
    __shared__ float part[3][256];
    const int id = blockIdx.x;
    const int t = threadIdx.x;
    if (id < 64) {
        // ---- transpose+convert one 64x64 tile (1024 threads: 1 float4 load, 1 uint2 store) ----
        const int k0 = (id & 3) * 64, n0 = (id >> 2) * 64;
        const int r = t >> 4, c4 = (t & 15) * 4;
        const float4 v = *(const float4*)(W1 + (size_t)(k0 + r) * 1024 + n0 + c4);
        tile[r][c4 + 0] = v.x; tile[r][c4 + 1] = v.y;
        tile[r][c4 + 2] = v.z; tile[r][c4 + 3] = v.w;
        __syncthreads();
        uint2 o;
        o.x = pack2h(tile[c4 + 0][r], tile[c4 + 1][r]);
        o.y = pack2h(tile[c4 + 2][r], tile[c4 + 3][r]);
        const int n  = n0 + r;          // 0..1023
        const int kk = k0 + c4;         // 0..255, multiple of 4
        const int it   = ((n >> 7) << 3) + (kk >> 5);
        const int rgrp = (n >> 4) & 7;
        const int lane = (((kk >> 3) & 3) << 4) + (n & 15);
        const size_t addr = (size_t)it * 4096 + rgrp * 512 + lane * 8 + (kk & 7);
        *(uint2*)(W1T + addr) = o;
    } else {
        // ---- corepart: 4-way K-split, 16 waves/block for latency hiding ----
        const int xb = id - 64;
        const int b = xb >> 2;                 // 0..63
        const int nl = t & 255;
        const int n = (xb & 3) * 256 + nl;     // 0..1023
        const int kq = t >> 8;                 // 0..3, each owns 128 k
        const float* cr = core + (size_t)b * K_CORE + kq * 128;
        const float* wp = W1 + (size_t)(K_EMB + kq * 128) * 1024 + n;
        float s0 = 0.f, s1 = 0.f, s2 = 0.f, s3 = 0.f;
#pragma unroll 8
        for (int k = 0; k < 128; k += 4) {
            s0 += cr[k + 0] * wp[(size_t)(k + 0) * 1024];
            s1 += cr[k + 1] * wp[(size_t)(k + 1) * 1024];
            s2 += cr[k + 2] * wp[(size_t)(k + 2) * 1024];
            s3 += cr[k + 3] * wp[(size_t)(k + 3) * 1024];
        }
        const float s = (s0 + s1) + (s2 + s3);
        if (kq) part[kq - 1][nl] = s;
        __syncthreads();
        if (kq == 0)
            cp[b * 1024 + n] = b1[n] + s + part[0][nl] + part[1][nl] + part[2][nl];
    }
}

// ---------- kernel 2 (fused): BM=32, 1024 blocks x 4 waves = 4096 waves = 16/CU.
// A-tile (32x256 f16, 16 KB, XOR-swizzled) staged ONCE in LDS -> cheap conflict-free
// ds_reads, no VGPR burden (fixes round-5 spill: VGPR 84 + scratch traffic).
// B streams global->VGPR from lane-permuted slabs: fully-contiguous 1 KB per load
// (round-5-validated: FETCH stays ~L2-resident). NO barriers, NO fences, NO glds
// in the loop -- compiler pipelines loads across the fully-unrolled iteration.
// LDS 22.5 KB; __launch_bounds__(256,4) caps VGPR at 128 (est. ~110) -> 4 waves/SIMD.
__global__ __launch_bounds__(256, 4) void fused_k(const float* __restrict__ emb,
                                                  const ushort_t* __restrict__ w1t,
                                                  const float* __restrict__ cp,
                                                  const float* __restrict__ W2,
                                                  const float* __restrict__ b2,
                                                  const int* __restrict__ nr_units,
                                                  const int* __restrict__ nr_flags,
                                                  float* __restrict__ out0,
                                                  float* __restrict__ out1) {
    __shared__ __align__(16) ushort_t Asl[32 * 256];     // 16 KB, row stride 512B, swizzle g^=(r&7)
    __shared__ __align__(16) float logitP[4][32][ACT];   // 6 KB, per-wave slots

    const int t = threadIdx.x;
    const int w = t >> 6, L = t & 63;
    const int lane16 = L & 15, qd = L >> 4;
    const int m0 = blockIdx.x * 32;
    const int bb = blockIdx.x >> 4;

    // ---- stage A tile: 32 rows x 256 k, f32 -> f16, XOR-swizzled (once per block) ----
    {
        const int g = t & 31;          // 8-f16 group within row (0..31)
        const int r0 = t >> 5;         // 0..7
#pragma unroll
        for (int p = 0; p < 4; ++p) {
            const int r = p * 8 + r0;
            const float* src = emb + (size_t)(m0 + r) * K_EMB + g * 8;
            const f32x4 v0 = __builtin_nontemporal_load((const f32x4*)src);
            const f32x4 v1 = __builtin_nontemporal_load((const f32x4*)src + 1);
            u32x4 pk;
            pk[0] = pack2h(v0[0], v0[1]); pk[1] = pack2h(v0[2], v0[3]);
            pk[2] = pack2h(v1[0], v1[1]); pk[3] = pack2h(v1[2], v1[3]);
            *(u32x4*)((char*)Asl + r * 512 + ((g ^ (r & 7)) << 4)) = pk;
        }
    }
    __syncthreads();   // A visible; only other barrier is before the softmax read

    // ---- A-fragment read bases (swizzled): row = mi*16+lane16, group = ks*4+qd ----
    const int araw0 = lane16 * 512;            // mi=0
    const int araw1 = (16 + lane16) * 512;     // mi=1 ((16+l)&7 == l&7 -> same XOR)
    const int axor = lane16 & 7;

    // ---- logit partials ----
    f32x4 la[2][3];
#pragma unroll
    for (int mi = 0; mi < 2; ++mi)
#pragma unroll
        for (int c = 0; c < 3; ++c) la[mi][c] = (f32x4){0.f, 0.f, 0.f, 0.f};

    // ---- main loop: 8 n-chunks of 32 within this wave's n-quarter ----
#pragma unroll
    for (int nc = 0; nc < 8; ++nc) {
        f32x4 acc[2][2];                 // [ni][mi]: D row=n(qd*4+r), col=m(lane16)
#pragma unroll
        for (int ni = 0; ni < 2; ++ni)
#pragma unroll
            for (int mi = 0; mi < 2; ++mi) acc[ni][mi] = (f32x4){0.f, 0.f, 0.f, 0.f};

        // slab base: it = (w*2 + nc/4)*8 + ks; chunk rgrp = (nc&3)*2 + ni
        const ushort_t* sb = w1t + (size_t)(w * 2 + (nc >> 2)) * 8 * 4096
                                 + ((nc & 3) * 2) * 512 + L * 8;
#pragma unroll
        for (int ks = 0; ks < 8; ++ks) {
            const f16x8 bf0 = *(const f16x8*)(sb + ks * 4096);
            const f16x8 bf1 = *(const f16x8*)(sb + ks * 4096 + 512);
            const int ga = (((ks << 2) | qd) ^ axor) << 4;
            const f16x8 af0 = *(const f16x8*)((const char*)Asl + araw0 + ga);
            const f16x8 af1 = *(const f16x8*)((const char*)Asl + araw1 + ga);
            acc[0][0] = __builtin_amdgcn_mfma_f32_16x16x32_f16(bf0, af0, acc[0][0], 0, 0, 0);
            acc[0][1] = __builtin_amdgcn_mfma_f32_16x16x32_f16(bf0, af1, acc[0][1], 0, 0, 0);
            acc[1][0] = __builtin_amdgcn_mfma_f32_16x16x32_f16(bf1, af0, acc[1][0], 0, 0, 0);
            acc[1][1] = __builtin_amdgcn_mfma_f32_16x16x32_f16(bf1, af1, acc[1][1], 0, 0, 0);
        }

        // ---- epilogue: +cp, relu, float4 out1 stores, logit partials ----
#pragma unroll
        for (int ni = 0; ni < 2; ++ni) {
            const int nbase = w * 256 + nc * 32 + ni * 16 + qd * 4;
            const f32x4 cpv = *(const f32x4*)(cp + bb * 1024 + nbase);
#pragma unroll
            for (int mi = 0; mi < 2; ++mi) {
                f32x4 v = acc[ni][mi] + cpv;
#pragma unroll
                for (int j = 0; j < 4; ++j) v[j] = v[j] > 0.f ? v[j] : 0.f;
                acc[ni][mi] = v;
                const size_t m = (size_t)(m0 + mi * 16 + lane16);
                __builtin_nontemporal_store(v, (f32x4*)(out1 + m * 1024 + nbase));
            }
#pragma unroll
            for (int r = 0; r < 4; ++r) {
                const f32x4* wp = (const f32x4*)(W2 + (size_t)(nbase + r) * ACT);
                const f32x4 w2a = wp[0], w2b = wp[1], w2c = wp[2];
#pragma unroll
                for (int mi = 0; mi < 2; ++mi) {
                    const float vv = acc[ni][mi][r];
                    la[mi][0] += w2a * vv;
                    la[mi][1] += w2b * vv;
                    la[mi][2] += w2c * vv;
                }
            }
        }
    }

    // ---- reduce logit partials across qd (lanes sharing lane16) ----
#pragma unroll
    for (int mi = 0; mi < 2; ++mi)
#pragma unroll
        for (int c = 0; c < 3; ++c)
#pragma unroll
            for (int j = 0; j < 4; ++j) {
                la[mi][c][j] += __shfl_xor(la[mi][c][j], 16, 64);
                la[mi][c][j] += __shfl_xor(la[mi][c][j], 32, 64);
            }
    if (qd == 0) {
#pragma unroll
        for (int mi = 0; mi < 2; ++mi) {
            f32x4* p = (f32x4*)&logitP[w][mi * 16 + lane16][0];
            p[0] = la[mi][0]; p[1] = la[mi][1]; p[2] = la[mi][2];
        }
    }
    __syncthreads();

    // ---- softmax + range mask, one thread per row ----
    if (t < 32) {
        float lg[ACT];
#pragma unroll
        for (int a = 0; a < ACT; ++a)
            lg[a] = logitP[0][t][a] + logitP[1][t][a]
                  + logitP[2][t][a] + logitP[3][t][a] + b2[a];
        float mx = lg[0];
#pragma unroll
        for (int a = 1; a < ACT; ++a) mx = fmaxf(mx, lg[a]);
        float s = 0.f;
#pragma unroll
        for (int a = 0; a < ACT; ++a) { lg[a] = __expf(lg[a] - mx); s += lg[a]; }
        const float inv = 1.f / s;
        const int m = m0 + t;
        const int u = m & 511;
        const float msk = (u >= nr_flags[bb] && u < nr_units[bb]) ? 1.0f : 1e-9f;
        f32x4 o0, o1, o2;
#pragma unroll
        for (int j = 0; j < 4; ++j) {
            o0[j] = lg[j] * inv * msk;
            o1[j] = lg[j + 4] * inv * msk;
            o2[j] = lg[j + 8] * inv * msk;
        }
        f32x4* op = (f32x4*)(out0 + (size_t)m * ACT);
        __builtin_nontemporal_store(o0, op + 0);
        __builtin_nontemporal_store(o1, op + 1);
        __builtin_nontemporal_store(o2, op + 2);
    }
}

extern "C" void kernel_launch(void* const* d_in, const int* in_sizes, int n_in,
                              void* d_out, int out_size, void* d_ws, size_t ws_size,
                              hipStream_t stream) {
    const float* core   = (const float*)d_in[0];
    const float* emb    = (const float*)d_in[1];
    const int* nr_units = (const int*)d_in[2];
    const int* nr_flags = (const int*)d_in[3];
    const float* W1     = (const float*)d_in[4];
    const float* b1     = (const float*)d_in[5];
    const float* W2     = (const float*)d_in[6];
    const float* b2     = (const float*)d_in[7];

    float* out0 = (float*)d_out;                       // probs [32768*12] f32
    float* out1 = out0 + (size_t)M_TOT * ACT;          // embedding [32768*1024] f32

    ushort_t* w1t = (ushort_t*)d_ws;                   // f16, lane-permuted slabs, 512 KB
    float* cp = (float*)((char*)d_ws + (size_t)1024 * 256 * 2); // [64][1024] f32

    prep_k<<<dim3(320), 1024, 0, stream>>>(W1, w1t, core, b1, cp);
    fused_k<<<dim3(1024), 256, 0, stream>>>(emb, w1t, cp, W2, b2, nr_units, nr_flags, out0, out1);
}